// Round 1
// baseline (280.779 us; speedup 1.0000x reference)
//
#include <hip/hip_runtime.h>
#include <hip/hip_bf16.h>

// TCFormer dynamic attention, MI355X. Pipeline:
//  k_weights: transpose/convert weights to bf16 [n][k] layouts
//  k_init:    zero padded k/v buffers, conf pads = -1e30
//  k_token2map: gather-average 4 tokens/cell -> kv_map bf16 [b][hw][c], conf_map
//  k_conv_ln: 4x4/s4 conv as (6272x2048)@(2048x128) MFMA GEMM + fused LayerNorm
//  k_kv:      kv_t @ kv_w -> k [bh][ns][d], v [bh][d][ns] (transposed for PV B-frags)
//  k_conf:    4x4 average pool of conf_map
//  k_q:       q_x @ q_w * SCALE -> qbuf bf16 [bh][n][d]
//  k_attn:    flash attention, QB=128 rows/block, 13 KV tiles of 64 (padded 832)
//  k_proj:    attbuf @ proj_w + proj_b -> f32 out

#define NBATCH 8
#define NQTOK  12544
#define NSP    832
#define QSCALE 0.125f

typedef __attribute__((ext_vector_type(8))) short bf8;
typedef __attribute__((ext_vector_type(4))) float f4;
typedef __attribute__((ext_vector_type(4))) unsigned short u16x4;

#define MFMA16(a, b, c) __builtin_amdgcn_mfma_f32_16x16x32_bf16((a), (b), (c), 0, 0, 0)

__device__ __forceinline__ unsigned short f2b(float x) {
  union { float f; unsigned u; } v; v.f = x;
  unsigned r = v.u + 0x7FFFu + ((v.u >> 16) & 1u);
  return (unsigned short)(r >> 16);
}

// MFMA fragment loader: lane holds tile[rbase + (lane&15)][kbase + 8*(lane>>4) .. +7]
// Used for A (rows=m) and for B via [n][k]-transposed tiles. 16B aligned (strides mult of 8).
__device__ __forceinline__ bf8 ldfrag(const unsigned short* t, int stride, int rbase, int kbase) {
  int lane = threadIdx.x & 63;
  return *(const bf8*)(t + (rbase + (lane & 15)) * stride + kbase + ((lane >> 4) << 3));
}

// ---------------- weights ----------------
__global__ void k_weights(const float* __restrict__ qw, const float* __restrict__ kvw,
                          const float* __restrict__ pw, const float* __restrict__ srw,
                          unsigned short* __restrict__ qwt, unsigned short* __restrict__ kvwt,
                          unsigned short* __restrict__ pwt, unsigned short* __restrict__ srwt) {
  int tid = blockIdx.x * 256 + threadIdx.x;
  int nt = gridDim.x * 256;
  for (int i = tid; i < 128 * 128; i += nt) {
    int k = i >> 7, n = i & 127;
    qwt[n * 128 + k] = f2b(qw[k * 128 + n]);
    pwt[n * 128 + k] = f2b(pw[k * 128 + n]);
  }
  for (int i = tid; i < 128 * 256; i += nt) {
    int k = i >> 8, j = i & 255;
    kvwt[j * 128 + k] = f2b(kvw[k * 256 + j]);
  }
  // srwt[o][kk], kk = (kh*4+kw)*128 + c  <-  sr_w[o][c][kh][kw]
  for (int i = tid; i < 128 * 2048; i += nt) {
    int o = i >> 11, kk = i & 2047;
    int p = kk >> 7, c = kk & 127;
    srwt[o * 2048 + kk] = f2b(srw[o * 2048 + c * 16 + p]);
  }
}

__global__ void k_init(unsigned* __restrict__ kb, unsigned* __restrict__ vb,
                       float* __restrict__ conf) {
  int tid = blockIdx.x * 256 + threadIdx.x;
  int nt = gridDim.x * 256;
  const int nu = NBATCH * 2 * NSP * 64 / 2;
  for (int i = tid; i < nu; i += nt) { kb[i] = 0u; vb[i] = 0u; }
  for (int i = tid; i < NBATCH * NSP; i += nt) conf[i] = -1e30f;
}

// ---------------- token2map ----------------
__global__ void k_token2map(const float* __restrict__ kv_x, const float* __restrict__ tsc,
                            const int* __restrict__ idxt,
                            unsigned short* __restrict__ kv_map, float* __restrict__ conf_map) {
  int half = threadIdx.x >> 7;
  int c = threadIdx.x & 127;
  int cell = blockIdx.x * 2 + half;          // < 100352
  int b = cell / 12544, hw = cell - b * 12544;
  int h = hw / 112, w = hw - h * 112;
  const int* it = idxt + b * 50176;
  int t0 = it[(2 * h) * 224 + 2 * w];
  int t1 = it[(2 * h) * 224 + 2 * w + 1];
  int t2 = it[(2 * h + 1) * 224 + 2 * w];
  int t3 = it[(2 * h + 1) * 224 + 2 * w + 1];
  const float* base = kv_x + (long)b * 12544 * 128;
  const float recip = 1.0f / (4.0f + 1e-6f);
  float s = base[t0 * 128 + c] + base[t1 * 128 + c] + base[t2 * 128 + c] + base[t3 * 128 + c];
  kv_map[(long)cell * 128 + c] = f2b(s * recip);
  if (c == 0) {
    const float* ts = tsc + b * 12544;
    conf_map[cell] = (ts[t0] + ts[t1] + ts[t2] + ts[t3]) * recip;
  }
}

// ---------------- conv (patch GEMM) + LayerNorm ----------------
__launch_bounds__(256)
__global__ void k_conv_ln(const unsigned short* __restrict__ kv_map,
                          const unsigned short* __restrict__ srwt,
                          const float* __restrict__ srb, const float* __restrict__ ng,
                          const float* __restrict__ nb, unsigned short* __restrict__ kv_t) {
  __shared__ unsigned short At[64 * 136];
  __shared__ unsigned short Bt[128 * 136];
  const int tid = threadIdx.x;
  const int lane = tid & 63, w = tid >> 6;
  const int l15 = lane & 15, g = lane >> 4;
  const int r0 = blockIdx.x * 64;
  const f4 fz = {0.f, 0.f, 0.f, 0.f};
  f4 acc[8];
#pragma unroll
  for (int i = 0; i < 8; i++) acc[i] = fz;

  for (int p = 0; p < 16; p++) {
#pragma unroll
    for (int j = 0; j < 4; j++) {                 // A: 64 x 128
      int id = tid + 256 * j;
      int row = id >> 4, c0 = (id & 15) << 3;
      int rr = r0 + row;
      int bb = rr / 784, pos = rr - bb * 784;
      int oh = pos / 28, ow = pos - oh * 28;
      long src = ((long)(bb * 12544 + (4 * oh + (p >> 2)) * 112 + 4 * ow + (p & 3))) * 128 + c0;
      *(uint4*)(At + row * 136 + c0) = *(const uint4*)(kv_map + src);
    }
#pragma unroll
    for (int j = 0; j < 8; j++) {                 // B: 128 x 128 slice of srwt
      int id = tid + 256 * j;
      int row = id >> 4, c0 = (id & 15) << 3;
      *(uint4*)(Bt + row * 136 + c0) = *(const uint4*)(srwt + row * 2048 + p * 128 + c0);
    }
    __syncthreads();
#pragma unroll
    for (int ks = 0; ks < 4; ks++) {
      bf8 a = ldfrag(At, 136, 16 * w, 32 * ks);
#pragma unroll
      for (int nf = 0; nf < 8; nf++) {
        bf8 bb = ldfrag(Bt, 136, 16 * nf, 32 * ks);
        acc[nf] = MFMA16(a, bb, acc[nf]);
      }
    }
    __syncthreads();
  }
  // epilogue: + sr_b, LayerNorm over 128 channels, write bf16
  float sum_[4] = {0.f, 0.f, 0.f, 0.f}, sq_[4] = {0.f, 0.f, 0.f, 0.f};
#pragma unroll
  for (int nf = 0; nf < 8; nf++) {
    float bias = srb[16 * nf + l15];
#pragma unroll
    for (int reg = 0; reg < 4; reg++) {
      float v = acc[nf][reg] + bias;
      acc[nf][reg] = v;
      sum_[reg] += v;
      sq_[reg] += v * v;
    }
  }
#pragma unroll
  for (int msk = 1; msk < 16; msk <<= 1)
#pragma unroll
    for (int reg = 0; reg < 4; reg++) {
      sum_[reg] += __shfl_xor(sum_[reg], msk, 64);
      sq_[reg] += __shfl_xor(sq_[reg], msk, 64);
    }
  float mean[4], rstd[4];
#pragma unroll
  for (int reg = 0; reg < 4; reg++) {
    mean[reg] = sum_[reg] * (1.0f / 128.0f);
    float var = sq_[reg] * (1.0f / 128.0f) - mean[reg] * mean[reg];
    rstd[reg] = rsqrtf(var + 1e-5f);
  }
#pragma unroll
  for (int nf = 0; nf < 8; nf++) {
    float gc = ng[16 * nf + l15], bc = nb[16 * nf + l15];
#pragma unroll
    for (int reg = 0; reg < 4; reg++) {
      int row = r0 + 16 * w + 4 * g + reg;
      float v = (acc[nf][reg] - mean[reg]) * rstd[reg] * gc + bc;
      kv_t[row * 128 + 16 * nf + l15] = f2b(v);
    }
  }
}

// ---------------- kv projection -> k, v ----------------
__launch_bounds__(256)
__global__ void k_kv(const unsigned short* __restrict__ kv_t,
                     const unsigned short* __restrict__ kvwt,
                     unsigned short* __restrict__ kbuf, unsigned short* __restrict__ vbuf) {
  __shared__ unsigned short At[64 * 136];
  __shared__ unsigned short Bt[128 * 136];
  const int tid = threadIdx.x;
  const int lane = tid & 63, w = tid >> 6;
  const int l15 = lane & 15, g = lane >> 4;
  const int r0 = blockIdx.x * 64;
  const int sel = blockIdx.y;                     // 0 -> k, 1 -> v
#pragma unroll
  for (int j = 0; j < 4; j++) {
    int id = tid + 256 * j;
    int row = id >> 4, c0 = (id & 15) << 3;
    *(uint4*)(At + row * 136 + c0) = *(const uint4*)(kv_t + (long)(r0 + row) * 128 + c0);
  }
#pragma unroll
  for (int j = 0; j < 8; j++) {
    int id = tid + 256 * j;
    int row = id >> 4, c0 = (id & 15) << 3;
    *(uint4*)(Bt + row * 136 + c0) = *(const uint4*)(kvwt + (long)(sel * 128 + row) * 128 + c0);
  }
  __syncthreads();
  const f4 fz = {0.f, 0.f, 0.f, 0.f};
  f4 acc[8];
#pragma unroll
  for (int i = 0; i < 8; i++) acc[i] = fz;
#pragma unroll
  for (int ks = 0; ks < 4; ks++) {
    bf8 a = ldfrag(At, 136, 16 * w, 32 * ks);
#pragma unroll
    for (int nf = 0; nf < 8; nf++) {
      bf8 bb = ldfrag(Bt, 136, 16 * nf, 32 * ks);
      acc[nf] = MFMA16(a, bb, acc[nf]);
    }
  }
#pragma unroll
  for (int nf = 0; nf < 8; nf++)
#pragma unroll
    for (int reg = 0; reg < 4; reg++) {
      int r = r0 + 16 * w + 4 * g + reg;
      int b = r / 784, ns = r - b * 784;
      int j = 16 * nf + l15;
      int hh = j >> 6, d = j & 63;
      unsigned short val = f2b(acc[nf][reg]);
      if (sel == 0) kbuf[((long)(b * 2 + hh) * NSP + ns) * 64 + d] = val;
      else          vbuf[((long)(b * 2 + hh) * 64 + d) * NSP + ns] = val;
    }
}

// ---------------- conf 4x4 average pool ----------------
__global__ void k_conf(const float* __restrict__ conf_map, float* __restrict__ conf) {
  int idx = blockIdx.x * 256 + threadIdx.x;
  if (idx >= NBATCH * 784) return;
  int b = idx / 784, pos = idx - b * 784;
  int oh = pos / 28, ow = pos - oh * 28;
  float s = 0.f;
#pragma unroll
  for (int kh = 0; kh < 4; kh++)
#pragma unroll
    for (int kw = 0; kw < 4; kw++)
      s += conf_map[b * 12544 + (4 * oh + kh) * 112 + 4 * ow + kw];
  conf[b * NSP + pos] = s * (1.0f / 16.0f);
}

// ---------------- q GEMM ----------------
__launch_bounds__(256)
__global__ void k_q(const float* __restrict__ q_x, const unsigned short* __restrict__ qwt,
                    unsigned short* __restrict__ qbuf) {
  __shared__ unsigned short At[64 * 136];
  __shared__ unsigned short Bt[128 * 136];
  const int tid = threadIdx.x;
  const int lane = tid & 63, w = tid >> 6;
  const int l15 = lane & 15, g = lane >> 4;
  const int r0 = blockIdx.x * 64;
#pragma unroll
  for (int j = 0; j < 8; j++) {                   // A: f32 -> bf16 convert, 64 x 128
    int id = tid + 256 * j;
    int row = id >> 5, c0 = (id & 31) << 2;
    float4 v = *(const float4*)(q_x + (long)(r0 + row) * 128 + c0);
    u16x4 o;
    o[0] = f2b(v.x); o[1] = f2b(v.y); o[2] = f2b(v.z); o[3] = f2b(v.w);
    *(u16x4*)(At + row * 136 + c0) = o;
  }
#pragma unroll
  for (int j = 0; j < 8; j++) {
    int id = tid + 256 * j;
    int row = id >> 4, c0 = (id & 15) << 3;
    *(uint4*)(Bt + row * 136 + c0) = *(const uint4*)(qwt + (long)row * 128 + c0);
  }
  __syncthreads();
  const f4 fz = {0.f, 0.f, 0.f, 0.f};
  f4 acc[8];
#pragma unroll
  for (int i = 0; i < 8; i++) acc[i] = fz;
#pragma unroll
  for (int ks = 0; ks < 4; ks++) {
    bf8 a = ldfrag(At, 136, 16 * w, 32 * ks);
#pragma unroll
    for (int nf = 0; nf < 8; nf++) {
      bf8 bb = ldfrag(Bt, 136, 16 * nf, 32 * ks);
      acc[nf] = MFMA16(a, bb, acc[nf]);
    }
  }
#pragma unroll
  for (int nf = 0; nf < 8; nf++)
#pragma unroll
    for (int reg = 0; reg < 4; reg++) {
      int r = r0 + 16 * w + 4 * g + reg;
      int b = r / NQTOK, n = r - b * NQTOK;
      int j = 16 * nf + l15;
      int hh = j >> 6, d = j & 63;
      qbuf[((long)(b * 2 + hh) * NQTOK + n) * 64 + d] = f2b(acc[nf][reg] * QSCALE);
    }
}

// ---------------- flash attention ----------------
__launch_bounds__(256, 2)
__global__ void k_attn(const unsigned short* __restrict__ qbuf,
                       const unsigned short* __restrict__ kbuf,
                       const unsigned short* __restrict__ vbuf,
                       const float* __restrict__ conf,
                       unsigned short* __restrict__ attbuf) {
  __shared__ unsigned short Qt[128 * 72];
  __shared__ unsigned short Kt[64 * 72];
  __shared__ unsigned short Vt[64 * 72];          // [d][kv]
  __shared__ unsigned short Pt[4][32 * 72];       // per-wave P strip
  const int tid = threadIdx.x;
  const int lane = tid & 63, w = tid >> 6;
  const int l15 = lane & 15, g = lane >> 4;
  const int h = blockIdx.y, b = blockIdx.z;
  const int bh = b * 2 + h;
  const int q0 = blockIdx.x * 128;
  const unsigned short* qsrc = qbuf + ((long)bh * NQTOK + q0) * 64;
#pragma unroll
  for (int j = 0; j < 4; j++) {
    int id = tid + 256 * j;
    int row = id >> 3, c0 = (id & 7) << 3;
    *(uint4*)(Qt + row * 72 + c0) = *(const uint4*)(qsrc + row * 64 + c0);
  }
  const f4 fz = {0.f, 0.f, 0.f, 0.f};
  f4 ao[2][4];
  float mreg[2][4], lreg[2][4];
#pragma unroll
  for (int mr = 0; mr < 2; mr++)
#pragma unroll
    for (int i = 0; i < 4; i++) { ao[mr][i] = fz; mreg[mr][i] = -1e30f; lreg[mr][i] = 0.f; }
  const float* confb = conf + b * NSP;
  const unsigned short* ksrc = kbuf + (long)bh * NSP * 64;
  const unsigned short* vsrc = vbuf + (long)bh * 64 * NSP;

  for (int t = 0; t < 13; t++) {
    const int kb0 = t * 64;
#pragma unroll
    for (int j = 0; j < 2; j++) {
      int id = tid + 256 * j;
      int row = id >> 3, c0 = (id & 7) << 3;
      *(uint4*)(Kt + row * 72 + c0) = *(const uint4*)(ksrc + (kb0 + row) * 64 + c0);
      *(uint4*)(Vt + row * 72 + c0) = *(const uint4*)(vsrc + row * NSP + kb0 + c0);
    }
    __syncthreads();
    f4 s_[2][4];
#pragma unroll
    for (int mr = 0; mr < 2; mr++)
#pragma unroll
      for (int nf = 0; nf < 4; nf++) s_[mr][nf] = fz;
#pragma unroll
    for (int ks = 0; ks < 2; ks++) {
      bf8 a0 = ldfrag(Qt, 72, 32 * w, 32 * ks);
      bf8 a1 = ldfrag(Qt, 72, 32 * w + 16, 32 * ks);
#pragma unroll
      for (int nf = 0; nf < 4; nf++) {
        bf8 kf = ldfrag(Kt, 72, 16 * nf, 32 * ks);
        s_[0][nf] = MFMA16(a0, kf, s_[0][nf]);
        s_[1][nf] = MFMA16(a1, kf, s_[1][nf]);
      }
    }
    float cv[4];
#pragma unroll
    for (int nf = 0; nf < 4; nf++) cv[nf] = confb[kb0 + 16 * nf + l15];
    float mx[2][4];
#pragma unroll
    for (int mr = 0; mr < 2; mr++)
#pragma unroll
      for (int reg = 0; reg < 4; reg++) {
        float m0 = s_[mr][0][reg] + cv[0];
        s_[mr][0][reg] = m0;
#pragma unroll
        for (int nf = 1; nf < 4; nf++) {
          float vv = s_[mr][nf][reg] + cv[nf];
          s_[mr][nf][reg] = vv;
          m0 = fmaxf(m0, vv);
        }
        mx[mr][reg] = m0;
      }
#pragma unroll
    for (int msk = 1; msk < 16; msk <<= 1)
#pragma unroll
      for (int mr = 0; mr < 2; mr++)
#pragma unroll
        for (int reg = 0; reg < 4; reg++)
          mx[mr][reg] = fmaxf(mx[mr][reg], __shfl_xor(mx[mr][reg], msk, 64));
    float sc[2][4], ls[2][4];
#pragma unroll
    for (int mr = 0; mr < 2; mr++)
#pragma unroll
      for (int reg = 0; reg < 4; reg++) {
        float mn = fmaxf(mreg[mr][reg], mx[mr][reg]);
        sc[mr][reg] = __expf(mreg[mr][reg] - mn);
        mreg[mr][reg] = mn;
        ls[mr][reg] = 0.f;
      }
#pragma unroll
    for (int mr = 0; mr < 2; mr++)
#pragma unroll
      for (int nf = 0; nf < 4; nf++)
#pragma unroll
        for (int reg = 0; reg < 4; reg++) {
          float pp = __expf(s_[mr][nf][reg] - mreg[mr][reg]);
          s_[mr][nf][reg] = pp;
          ls[mr][reg] += pp;
        }
#pragma unroll
    for (int msk = 1; msk < 16; msk <<= 1)
#pragma unroll
      for (int mr = 0; mr < 2; mr++)
#pragma unroll
        for (int reg = 0; reg < 4; reg++)
          ls[mr][reg] += __shfl_xor(ls[mr][reg], msk, 64);
#pragma unroll
    for (int mr = 0; mr < 2; mr++)
#pragma unroll
      for (int reg = 0; reg < 4; reg++)
        lreg[mr][reg] = lreg[mr][reg] * sc[mr][reg] + ls[mr][reg];
#pragma unroll
    for (int mr = 0; mr < 2; mr++)
#pragma unroll
      for (int nfd = 0; nfd < 4; nfd++)
#pragma unroll
        for (int reg = 0; reg < 4; reg++)
          ao[mr][nfd][reg] *= sc[mr][reg];
    unsigned short* ptw = &Pt[w][0];
#pragma unroll
    for (int mr = 0; mr < 2; mr++)
#pragma unroll
      for (int nf = 0; nf < 4; nf++)
#pragma unroll
        for (int reg = 0; reg < 4; reg++)
          ptw[(16 * mr + 4 * g + reg) * 72 + 16 * nf + l15] = f2b(s_[mr][nf][reg]);
    __syncthreads();
#pragma unroll
    for (int ks = 0; ks < 2; ks++) {
      bf8 p0 = ldfrag(ptw, 72, 0, 32 * ks);
      bf8 p1 = ldfrag(ptw, 72, 16, 32 * ks);
#pragma unroll
      for (int nfd = 0; nfd < 4; nfd++) {
        bf8 vf = ldfrag(Vt, 72, 16 * nfd, 32 * ks);
        ao[0][nfd] = MFMA16(p0, vf, ao[0][nfd]);
        ao[1][nfd] = MFMA16(p1, vf, ao[1][nfd]);
      }
    }
    __syncthreads();
  }
#pragma unroll
  for (int mr = 0; mr < 2; mr++) {
    float inv[4];
#pragma unroll
    for (int reg = 0; reg < 4; reg++) inv[reg] = 1.0f / lreg[mr][reg];
#pragma unroll
    for (int nfd = 0; nfd < 4; nfd++)
#pragma unroll
      for (int reg = 0; reg < 4; reg++) {
        int n = q0 + 32 * w + 16 * mr + 4 * g + reg;
        int col = h * 64 + 16 * nfd + l15;
        attbuf[((long)b * NQTOK + n) * 128 + col] = f2b(ao[mr][nfd][reg] * inv[reg]);
      }
  }
}

// ---------------- final projection ----------------
__launch_bounds__(256)
__global__ void k_proj(const unsigned short* __restrict__ attbuf,
                       const unsigned short* __restrict__ pwt,
                       const float* __restrict__ pb, float* __restrict__ out) {
  __shared__ unsigned short At[64 * 136];
  __shared__ unsigned short Bt[128 * 136];
  const int tid = threadIdx.x;
  const int lane = tid & 63, w = tid >> 6;
  const int l15 = lane & 15, g = lane >> 4;
  const int r0 = blockIdx.x * 64;
#pragma unroll
  for (int j = 0; j < 4; j++) {
    int id = tid + 256 * j;
    int row = id >> 4, c0 = (id & 15) << 3;
    *(uint4*)(At + row * 136 + c0) = *(const uint4*)(attbuf + (long)(r0 + row) * 128 + c0);
  }
#pragma unroll
  for (int j = 0; j < 8; j++) {
    int id = tid + 256 * j;
    int row = id >> 4, c0 = (id & 15) << 3;
    *(uint4*)(Bt + row * 136 + c0) = *(const uint4*)(pwt + (long)row * 128 + c0);
  }
  __syncthreads();
  const f4 fz = {0.f, 0.f, 0.f, 0.f};
  f4 acc[8];
#pragma unroll
  for (int i = 0; i < 8; i++) acc[i] = fz;
#pragma unroll
  for (int ks = 0; ks < 4; ks++) {
    bf8 a = ldfrag(At, 136, 16 * w, 32 * ks);
#pragma unroll
    for (int nf = 0; nf < 8; nf++) {
      bf8 bb = ldfrag(Bt, 136, 16 * nf, 32 * ks);
      acc[nf] = MFMA16(a, bb, acc[nf]);
    }
  }
#pragma unroll
  for (int nf = 0; nf < 8; nf++) {
    float bias = pb[16 * nf + l15];
#pragma unroll
    for (int reg = 0; reg < 4; reg++) {
      int r = r0 + 16 * w + 4 * g + reg;
      out[(long)r * 128 + 16 * nf + l15] = acc[nf][reg] + bias;
    }
  }
}

extern "C" void kernel_launch(void* const* d_in, const int* in_sizes, int n_in,
                              void* d_out, int out_size, void* d_ws, size_t ws_size,
                              hipStream_t stream) {
  const float* q_x  = (const float*)d_in[0];
  const float* kv_x = (const float*)d_in[1];
  const float* tsc  = (const float*)d_in[2];
  const int*   idxt = (const int*)d_in[3];
  const float* q_w  = (const float*)d_in[8];
  const float* kv_w = (const float*)d_in[9];
  const float* pw   = (const float*)d_in[10];
  const float* pb   = (const float*)d_in[11];
  const float* srw  = (const float*)d_in[12];
  const float* srb  = (const float*)d_in[13];
  const float* ng   = (const float*)d_in[14];
  const float* nb   = (const float*)d_in[15];
  float* outp = (float*)d_out;

  char* ws = (char*)d_ws;
  size_t off = 0;
  auto take = [&](size_t bytes) {
    char* p = ws + off;
    off += (bytes + 255) & ~(size_t)255;
    return p;
  };
  unsigned short* qwt   = (unsigned short*)take(128 * 128 * 2);
  unsigned short* pwt   = (unsigned short*)take(128 * 128 * 2);
  unsigned short* kvwt  = (unsigned short*)take(256 * 128 * 2);
  unsigned short* srwt  = (unsigned short*)take(128 * 2048 * 2);
  unsigned short* kvmap = (unsigned short*)take((size_t)NBATCH * 12544 * 128 * 2);
  float* conf_map       = (float*)take((size_t)NBATCH * 12544 * 4);
  unsigned short* kvt   = (unsigned short*)take((size_t)NBATCH * 784 * 128 * 2);
  unsigned short* kbuf  = (unsigned short*)take((size_t)NBATCH * 2 * NSP * 64 * 2);
  unsigned short* vbuf  = (unsigned short*)take((size_t)NBATCH * 2 * NSP * 64 * 2);
  float* conf           = (float*)take((size_t)NBATCH * NSP * 4);
  unsigned short* qbuf  = (unsigned short*)take((size_t)NBATCH * 2 * NQTOK * 64 * 2);
  unsigned short* attbuf = kvmap;  // kv_map dead after k_conv_ln; reuse for attention out

  k_weights<<<256, 256, 0, stream>>>(q_w, kv_w, pw, srw, qwt, kvwt, pwt, srwt);
  k_init<<<512, 256, 0, stream>>>((unsigned*)kbuf, (unsigned*)vbuf, conf);
  k_token2map<<<50176, 256, 0, stream>>>(kv_x, tsc, idxt, kvmap, conf_map);
  k_conv_ln<<<98, 256, 0, stream>>>(kvmap, srwt, srb, ng, nb, kvt);
  k_kv<<<dim3(98, 2), 256, 0, stream>>>(kvt, kvwt, kbuf, vbuf);
  k_conf<<<25, 256, 0, stream>>>(conf_map, conf);
  k_q<<<1568, 256, 0, stream>>>(q_x, qwt, qbuf);
  k_attn<<<dim3(98, 2, 8), 256, 0, stream>>>(qbuf, kbuf, vbuf, conf, attbuf);
  k_proj<<<1568, 256, 0, stream>>>(attbuf, pwt, pb, outp);
}